// Round 16
// baseline (555.128 us; speedup 1.0000x reference)
//
#include <hip/hip_runtime.h>
#include <hip/hip_fp8.h>

typedef __bf16 bf16x8 __attribute__((ext_vector_type(8)));
typedef float  f32x4  __attribute__((ext_vector_type(4)));
typedef float  f32x16 __attribute__((ext_vector_type(16)));
typedef int    i32x4v __attribute__((ext_vector_type(4)));
typedef int    i32x8v __attribute__((ext_vector_type(8)));
typedef unsigned char uchar16v __attribute__((ext_vector_type(16)));

#define NROWS 8192
#define DK    4096
#define MCOLS 4096

// ---- fp8 path geometry: BK=128 ---------------------------------------------
#define NKT2   32            // K-tiles of BK=128
#define IMGB   32768         // bytes per 256x128 fp8 tile image (32 KB)
#define REGB   16384         // region bytes (ki half)
#define XT2    32            // 8192/256
#define WT2    16            // 4096/256

#define X_BYTES ((size_t)XT2 * NKT2 * IMGB)   // 33.5 MB
#define W_BYTES ((size_t)WT2 * NKT2 * IMGB)   // 16.8 MB
#define WS_NEED (X_BYTES + W_BYTES)

#define BAR()  do { __builtin_amdgcn_s_barrier(); asm volatile("" ::: "memory"); } while (0)
#define VM0    asm volatile("s_waitcnt vmcnt(0)" ::: "memory")

__device__ __forceinline__ void gload16(const unsigned char* g, unsigned char* l) {
  __builtin_amdgcn_global_load_lds(
      (const __attribute__((address_space(1))) void*)g,
      (__attribute__((address_space(3))) void*)l, 16, 0, 0);
}

// fp32 row-major -> e4m3 fragment image:
// [tile][kt'][ki 0..1][slot 0..7][half 0..1][lane 0..63][16B]
__global__ __launch_bounds__(256) void convF8(const float* __restrict__ src,
                                              unsigned char* __restrict__ dst,
                                              int ntiles, float scale) {
  const int total = ntiles * 65536;
  for (int i = blockIdx.x * blockDim.x + threadIdx.x; i < total;
       i += gridDim.x * blockDim.x) {
    int lane = i & 63;
    int half = (i >> 6) & 1;
    int slot = (i >> 7) & 7;
    int ki   = (i >> 10) & 1;
    int kt   = (i >> 11) & 31;
    int tm   = i >> 16;
    int row = tm * 256 + slot * 32 + (lane & 31);
    int k   = kt * 128 + ki * 64 + (lane >> 5) * 32 + half * 16;
    const float4* p = (const float4*)(src + (size_t)row * DK + k);
    uchar16v o;
#pragma unroll
    for (int q = 0; q < 4; ++q) {
      float4 f = p[q];
      o[q * 4 + 0] = __hip_fp8_e4m3(f.x * scale).__x;
      o[q * 4 + 1] = __hip_fp8_e4m3(f.y * scale).__x;
      o[q * 4 + 2] = __hip_fp8_e4m3(f.z * scale).__x;
      o[q * 4 + 3] = __hip_fp8_e4m3(f.w * scale).__x;
    }
    *(uchar16v*)(dst + (size_t)i * 16) = o;
  }
}

// ---- X-in-registers (from L2-resident ws), W 2-buf LDS, 1 VM0+BAR per tile -
__global__ __launch_bounds__(512, 2) void gemm19(const unsigned char* __restrict__ wsX,
                                                 const unsigned char* __restrict__ wsW,
                                                 float* __restrict__ out) {
  __shared__ __align__(16) unsigned char Wls[2][IMGB];   // 64 KB
  __shared__ float rowsum[2][256];

  const int t    = threadIdx.x;
  const int lane = t & 63;
  const int w    = t >> 6;           // 0..7
  const int wr4  = w >> 1;           // rows wr4*64..+63 (slots 2wr4, 2wr4+1)
  const int wc2  = w & 1;            // cols wc2*128..+127 (slots wc2*4..+3)
  const int hi   = lane >> 5;

  unsigned bid = blockIdx.x;
  unsigned xcd = bid & 7, seq = bid >> 3;
  const int tile_m = (int)((xcd >> 1) * 8 + (seq & 7));    // 0..31
  const int tile_n = (int)((xcd & 1) * 8 + (seq >> 3));    // 0..15

  const unsigned char* xbase = wsX + (size_t)tile_m * ((size_t)NKT2 * IMGB);
  const unsigned char* wbase = wsW + (size_t)tile_n * ((size_t)NKT2 * IMGB);

  // per-wave X fragment base in the global image (slots 2wr4, 2wr4+1)
  const unsigned char* xw = xbase + wr4 * 4096 + (size_t)lane * 16;
  const unsigned char* pW0 = &Wls[0][0] + wc2 * 8192 + lane * 16;
  const unsigned char* pW1 = &Wls[1][0] + wc2 * 8192 + lane * 16;

  f32x16 acc[2][4] = {};     // [mt][nf] : 128 VGPR
  i32x8v xa[2][2], xb[2][2]; // [ki][mt] : 32+32 VGPR
  i32x8v bU[2], bV[2];       // 16+16 VGPR

  auto ld32 = [&](const unsigned char* p) {   // 2x b128 (LDS or global by addrspace)
    i32x4v lo = *(const i32x4v*)p;
    i32x4v hh = *(const i32x4v*)(p + 1024);
    i32x8v r;
    r[0] = lo[0]; r[1] = lo[1]; r[2] = lo[2]; r[3] = lo[3];
    r[4] = hh[0]; r[5] = hh[1]; r[6] = hh[2]; r[7] = hh[3];
    return r;
  };

  auto loadXg = [&](i32x8v (&x)[2][2], int h) {   // 8 coalesced global b128
    const unsigned char* p = xw + (size_t)h * IMGB;
#pragma unroll
    for (int ki = 0; ki < 2; ++ki)
#pragma unroll
      for (int mt = 0; mt < 2; ++mt)
        x[ki][mt] = ld32(p + ki * REGB + mt * 2048);
  };

  auto readB = [&](i32x8v (&b)[2], const unsigned char* p, int ki, int bh) { // 4 ds_read
#pragma unroll
    for (int nf2 = 0; nf2 < 2; ++nf2)
      b[nf2] = ld32(p + ki * REGB + (bh * 2 + nf2) * 2048);
  };

  auto quad = [&](const i32x8v (&a2)[2], const i32x8v (&b)[2], int bh) {  // 4 MFMA
    __builtin_amdgcn_s_setprio(1);
#pragma unroll
    for (int mt = 0; mt < 2; ++mt)
#pragma unroll
      for (int nf2 = 0; nf2 < 2; ++nf2)
        acc[mt][bh * 2 + nf2] = __builtin_amdgcn_mfma_scale_f32_32x32x64_f8f6f4(
            a2[mt], b[nf2], acc[mt][bh * 2 + nf2],
            0, 0,                    // cbsz/blgp = FP8 e4m3
            0, 0x7F7F7F7F,           // scale A = 1.0
            0, 0x7F7F7F7F);          // scale B = 1.0
    __builtin_amdgcn_s_setprio(0);
  };

  auto stage = [&](const unsigned char* srcImg, int regionOff, unsigned char* ldsImg) {
    const unsigned char* s0 = srcImg + regionOff + t * 16;
    unsigned char* d0 = ldsImg + regionOff + w * 1024;   // wave-uniform dst
    gload16(s0, d0);
    gload16(s0 + 8192, d0 + 8192);
  };

  // tile body: single VM0+BAR at end (count-independent; race-class-free).
  // Prefetch X(h+1) to regs and stage W(h+1) to the other LDS buffer.
  auto tile = [&](int h, i32x8v (&xcur)[2][2], i32x8v (&xnext)[2][2]) {
    const unsigned char* Wcur = (h & 1) ? pW1 : pW0;
    unsigned char* Wnxt = &Wls[(h + 1) & 1][0];
    readB(bU, Wcur, 0, 0);
    readB(bV, Wcur, 0, 1);
    if (h + 1 < NKT2) {
      loadXg(xnext, h + 1);                      // 8 global b128 (plain)
      const unsigned char* wsrc = wbase + (size_t)(h + 1) * IMGB;
      stage(wsrc, 0,    Wnxt);                   // 4 gload16 total
      stage(wsrc, REGB, Wnxt);
    }
    quad(xcur[0], bU, 0);
    readB(bU, Wcur, 1, 0);
    quad(xcur[0], bV, 1);
    readB(bV, Wcur, 1, 1);
    quad(xcur[1], bU, 0);
    quad(xcur[1], bV, 1);
    VM0;                                         // X(h+1)+W(h+1) landed (issued ~2k cyc ago)
    BAR();                                       // Wnxt visible; Wcur reads all done
  };

  // prologue
  stage(wbase, 0,    &Wls[0][0]);
  stage(wbase, REGB, &Wls[0][0]);
  loadXg(xa, 0);
  VM0;
  BAR();

  for (int h = 0; h < NKT2; h += 2) {
    tile(h,     xa, xb);
    tile(h + 1, xb, xa);
  }

  // ---- epilogue: row sums of squares; undo 64x A-scale (x 2^-12) -----------
  // acc[mt][nf] reg r: row = tile_m*256 + (wr4*2+mt)*32 + (r&3) + 8*(r>>2) + 4*hi
  float v[2][16];
#pragma unroll
  for (int mt = 0; mt < 2; ++mt)
#pragma unroll
    for (int r = 0; r < 16; ++r) {
      float s = 0.f;
#pragma unroll
      for (int nf = 0; nf < 4; ++nf) {
        float c = acc[mt][nf][r];
        s += c * c;
      }
      s += __shfl_xor(s, 1, 64);
      s += __shfl_xor(s, 2, 64);
      s += __shfl_xor(s, 4, 64);
      s += __shfl_xor(s, 8, 64);
      s += __shfl_xor(s, 16, 64);
      v[mt][r] = s;
    }

  if ((lane & 31) == 0) {
#pragma unroll
    for (int mt = 0; mt < 2; ++mt)
#pragma unroll
      for (int r = 0; r < 16; ++r)
        rowsum[wc2][(wr4 * 2 + mt) * 32 + (r & 3) + 8 * (r >> 2) + 4 * hi] = v[mt][r];
  }
  __syncthreads();

  if (t < 256) {
    float p = (rowsum[0][t] + rowsum[1][t]) * (1.0f / 4096.0f);
    atomicAdd(&out[tile_m * 256 + t], p);
  }
}

// ---------------- fallback (direct fp32 path, used only if ws too small) ----
__device__ __forceinline__ bf16x8 pack8(const float4& a, const float4& b) {
  bf16x8 r;
  r[0] = (__bf16)a.x; r[1] = (__bf16)a.y; r[2] = (__bf16)a.z; r[3] = (__bf16)a.w;
  r[4] = (__bf16)b.x; r[5] = (__bf16)b.y; r[6] = (__bf16)b.z; r[7] = (__bf16)b.w;
  return r;
}

struct Stage {
  float4 x0a, x0b, x1a, x1b;
  float4 a0a, a0b, a1a, a1b;
};

__global__ __launch_bounds__(256) void gemm_rowsq(const float* __restrict__ X,
                                                  const float* __restrict__ A,
                                                  float* __restrict__ out) {
  __shared__ __align__(16) __bf16 Xs[128 * 32];
  __shared__ __align__(16) __bf16 As[128 * 32];
  __shared__ float rowsum[2][128];

  const int t    = threadIdx.x;
  const int lane = t & 63;
  const int wid  = t >> 6;
  const int wr   = wid >> 1;
  const int wc   = wid & 1;
  const int l15  = lane & 15;
  const int lg   = lane >> 4;

  unsigned bid = blockIdx.x;
  unsigned swz = (bid & 7) * 256u + (bid >> 3);
  const int tile_m = swz >> 5;
  const int tile_n = swz & 31;

  const int srow = t >> 2;
  const int sc   = t & 3;
  const int cw   = sc ^ ((t >> 3) & 3);
  const int woff = srow * 32 + cw * 8;

  const float* gx = X + (size_t)(tile_m * 128 + srow) * DK + sc * 8;
  const float* ga = A + (size_t)(tile_n * 128 + srow) * DK + sc * 8;

  const int chA  = lg ^ ((l15 >> 1) & 3);
  const int aoff = (wr * 64 + l15) * 32 + chA * 8;
  const int boff = (wc * 64 + l15) * 32 + chA * 8;

  f32x4 acc[4][4] = {};

  auto load_tile = [&](int kt) {
    Stage s;
    const float* px = gx + kt * 32;
    const float* pa = ga + kt * 32;
    s.x0a = *(const float4*)(px);
    s.x0b = *(const float4*)(px + 4);
    s.x1a = *(const float4*)(px + (size_t)64 * DK);
    s.x1b = *(const float4*)(px + (size_t)64 * DK + 4);
    s.a0a = *(const float4*)(pa);
    s.a0b = *(const float4*)(pa + 4);
    s.a1a = *(const float4*)(pa + (size_t)64 * DK);
    s.a1b = *(const float4*)(pa + (size_t)64 * DK + 4);
    return s;
  };

  auto store_stage = [&](const Stage& s) {
    *(bf16x8*)(Xs + woff)            = pack8(s.x0a, s.x0b);
    *(bf16x8*)(Xs + woff + 64 * 32)  = pack8(s.x1a, s.x1b);
    *(bf16x8*)(As + woff)            = pack8(s.a0a, s.a0b);
    *(bf16x8*)(As + woff + 64 * 32)  = pack8(s.a1a, s.a1b);
  };

  auto compute = [&]() {
    bf16x8 af[4], bfr[4];
#pragma unroll
    for (int m = 0; m < 4; ++m)
      af[m] = *(const bf16x8*)(Xs + aoff + m * 16 * 32);
#pragma unroll
    for (int n = 0; n < 4; ++n)
      bfr[n] = *(const bf16x8*)(As + boff + n * 16 * 32);
#pragma unroll
    for (int m = 0; m < 4; ++m)
#pragma unroll
      for (int n = 0; n < 4; ++n)
        acc[m][n] = __builtin_amdgcn_mfma_f32_16x16x32_bf16(af[m], bfr[n],
                                                            acc[m][n], 0, 0, 0);
  };

  Stage sa = load_tile(0), sb;

  for (int kt = 0; kt < 128; kt += 2) {
    __syncthreads();
    store_stage(sa);
    sb = load_tile(kt + 1);
    __syncthreads();
    compute();
    __syncthreads();
    store_stage(sb);
    if (kt + 2 < 128) sa = load_tile(kt + 2);
    __syncthreads();
    compute();
  }

  float v[4][4];
#pragma unroll
  for (int m = 0; m < 4; ++m)
#pragma unroll
    for (int j = 0; j < 4; ++j) {
      float s = 0.f;
#pragma unroll
      for (int n = 0; n < 4; ++n) {
        float c = acc[m][n][j];
        s += c * c;
      }
      s += __shfl_xor(s, 1, 64);
      s += __shfl_xor(s, 2, 64);
      s += __shfl_xor(s, 4, 64);
      s += __shfl_xor(s, 8, 64);
      v[m][j] = s;
    }

  if (l15 == 0) {
#pragma unroll
    for (int m = 0; m < 4; ++m)
#pragma unroll
      for (int j = 0; j < 4; ++j)
        rowsum[wc][wr * 64 + m * 16 + lg * 4 + j] = v[m][j];
  }
  __syncthreads();

  if (t < 128) {
    float p = rowsum[0][t] + rowsum[1][t];
    atomicAdd(&out[tile_m * 128 + t], p);
  }
}

extern "C" void kernel_launch(void* const* d_in, const int* in_sizes, int n_in,
                              void* d_out, int out_size, void* d_ws, size_t ws_size,
                              hipStream_t stream) {
  const float* x = (const float*)d_in[0];
  const float* A = (const float*)d_in[1];
  float* out = (float*)d_out;

  hipMemsetAsync(out, 0, (size_t)out_size * sizeof(float), stream);

  if (ws_size >= WS_NEED) {
    unsigned char* wsX = (unsigned char*)d_ws;
    unsigned char* wsW = wsX + X_BYTES;
    hipLaunchKernelGGL(convF8, dim3(2048), dim3(256), 0, stream, x, wsX, XT2, 1.0f);
    hipLaunchKernelGGL(convF8, dim3(2048), dim3(256), 0, stream, A, wsW, WT2, 64.0f);
    hipLaunchKernelGGL(gemm19, dim3(512), dim3(512), 0, stream, wsX, wsW, out);
  } else {
    hipLaunchKernelGGL(gemm_rowsq, dim3(2048), dim3(256), 0, stream, x, A, out);
  }
}

// Round 17
// 548.006 us; speedup vs baseline: 1.0130x; 1.0130x over previous
//
#include <hip/hip_runtime.h>
#include <hip/hip_fp8.h>

typedef __bf16 bf16x8 __attribute__((ext_vector_type(8)));
typedef float  f32x4  __attribute__((ext_vector_type(4)));
typedef float  f32x16 __attribute__((ext_vector_type(16)));
typedef int    i32x4v __attribute__((ext_vector_type(4)));
typedef int    i32x8v __attribute__((ext_vector_type(8)));
typedef unsigned char uchar16v __attribute__((ext_vector_type(16)));

#define NROWS 8192
#define DK    4096
#define MCOLS 4096

// ---- fp8 path geometry: BK=128 ---------------------------------------------
#define NKT2   32            // K-tiles of BK=128
#define IMGB   32768         // bytes per 256x128 fp8 tile image (32 KB)
#define REGB   16384         // region bytes (ki half)
#define XT2    32            // 8192/256
#define WT2    16            // 4096/256

#define X_BYTES ((size_t)XT2 * NKT2 * IMGB)   // 33.5 MB
#define W_BYTES ((size_t)WT2 * NKT2 * IMGB)   // 16.8 MB
#define WS_NEED (X_BYTES + W_BYTES)

#define BAR()  do { __builtin_amdgcn_s_barrier(); asm volatile("" ::: "memory"); } while (0)
#define VM0    asm volatile("s_waitcnt vmcnt(0)" ::: "memory")

__device__ __forceinline__ void gload16(const unsigned char* g, unsigned char* l) {
  __builtin_amdgcn_global_load_lds(
      (const __attribute__((address_space(1))) void*)g,
      (__attribute__((address_space(3))) void*)l, 16, 0, 0);
}

// fp32 row-major -> e4m3 fragment image:
// [tile][kt'][ki 0..1][slot 0..7][half 0..1][lane 0..63][16B]
__global__ __launch_bounds__(256) void convF8(const float* __restrict__ src,
                                              unsigned char* __restrict__ dst,
                                              int ntiles, float scale) {
  const int total = ntiles * 65536;
  for (int i = blockIdx.x * blockDim.x + threadIdx.x; i < total;
       i += gridDim.x * blockDim.x) {
    int lane = i & 63;
    int half = (i >> 6) & 1;
    int slot = (i >> 7) & 7;
    int ki   = (i >> 10) & 1;
    int kt   = (i >> 11) & 31;
    int tm   = i >> 16;
    int row = tm * 256 + slot * 32 + (lane & 31);
    int k   = kt * 128 + ki * 64 + (lane >> 5) * 32 + half * 16;
    const float4* p = (const float4*)(src + (size_t)row * DK + k);
    uchar16v o;
#pragma unroll
    for (int q = 0; q < 4; ++q) {
      float4 f = p[q];
      o[q * 4 + 0] = __hip_fp8_e4m3(f.x * scale).__x;
      o[q * 4 + 1] = __hip_fp8_e4m3(f.y * scale).__x;
      o[q * 4 + 2] = __hip_fp8_e4m3(f.z * scale).__x;
      o[q * 4 + 3] = __hip_fp8_e4m3(f.w * scale).__x;
    }
    *(uchar16v*)(dst + (size_t)i * 16) = o;
  }
}

// ---- X-in-registers, W 2-buf LDS, 1 VM0+BAR per tile.
// __launch_bounds__(512, 1): 2nd arg behaves as min BLOCKS/CU on this
// toolchain (R10/R16 evidence: 2 -> cap 128 VGPR, 4 -> cap 64). 1 -> cap 256.
__global__ __launch_bounds__(512, 1) void gemm19(const unsigned char* __restrict__ wsX,
                                                 const unsigned char* __restrict__ wsW,
                                                 float* __restrict__ out) {
  __shared__ __align__(16) unsigned char Wls[2][IMGB];   // 64 KB
  __shared__ float rowsum[2][256];

  const int t    = threadIdx.x;
  const int lane = t & 63;
  const int w    = t >> 6;           // 0..7
  const int wr4  = w >> 1;           // rows wr4*64..+63 (slots 2wr4, 2wr4+1)
  const int wc2  = w & 1;            // cols wc2*128..+127 (slots wc2*4..+3)
  const int hi   = lane >> 5;

  unsigned bid = blockIdx.x;
  unsigned xcd = bid & 7, seq = bid >> 3;
  const int tile_m = (int)((xcd >> 1) * 8 + (seq & 7));    // 0..31
  const int tile_n = (int)((xcd & 1) * 8 + (seq >> 3));    // 0..15

  const unsigned char* xbase = wsX + (size_t)tile_m * ((size_t)NKT2 * IMGB);
  const unsigned char* wbase = wsW + (size_t)tile_n * ((size_t)NKT2 * IMGB);

  // per-wave X fragment base in the global image (slots 2wr4, 2wr4+1)
  const unsigned char* xw = xbase + wr4 * 4096 + (size_t)lane * 16;
  const unsigned char* pW0 = &Wls[0][0] + wc2 * 8192 + lane * 16;
  const unsigned char* pW1 = &Wls[1][0] + wc2 * 8192 + lane * 16;

  f32x16 acc[2][4] = {};     // [mt][nf] : 128 VGPR
  i32x8v xa[2][2], xb[2][2]; // [ki][mt] : 32+32 VGPR
  i32x8v bU[2], bV[2];       // 16+16 VGPR

  auto ld32 = [&](const unsigned char* p) {   // 2x b128 (LDS or global by addrspace)
    i32x4v lo = *(const i32x4v*)p;
    i32x4v hh = *(const i32x4v*)(p + 1024);
    i32x8v r;
    r[0] = lo[0]; r[1] = lo[1]; r[2] = lo[2]; r[3] = lo[3];
    r[4] = hh[0]; r[5] = hh[1]; r[6] = hh[2]; r[7] = hh[3];
    return r;
  };

  auto loadXg = [&](i32x8v (&x)[2][2], int h) {   // 8 coalesced global b128
    const unsigned char* p = xw + (size_t)h * IMGB;
#pragma unroll
    for (int ki = 0; ki < 2; ++ki)
#pragma unroll
      for (int mt = 0; mt < 2; ++mt)
        x[ki][mt] = ld32(p + ki * REGB + mt * 2048);
  };

  auto readB = [&](i32x8v (&b)[2], const unsigned char* p, int ki, int bh) { // 4 ds_read
#pragma unroll
    for (int nf2 = 0; nf2 < 2; ++nf2)
      b[nf2] = ld32(p + ki * REGB + (bh * 2 + nf2) * 2048);
  };

  auto quad = [&](const i32x8v (&a2)[2], const i32x8v (&b)[2], int bh) {  // 4 MFMA
    __builtin_amdgcn_s_setprio(1);
#pragma unroll
    for (int mt = 0; mt < 2; ++mt)
#pragma unroll
      for (int nf2 = 0; nf2 < 2; ++nf2)
        acc[mt][bh * 2 + nf2] = __builtin_amdgcn_mfma_scale_f32_32x32x64_f8f6f4(
            a2[mt], b[nf2], acc[mt][bh * 2 + nf2],
            0, 0,                    // cbsz/blgp = FP8 e4m3
            0, 0x7F7F7F7F,           // scale A = 1.0
            0, 0x7F7F7F7F);          // scale B = 1.0
    __builtin_amdgcn_s_setprio(0);
  };

  auto stage = [&](const unsigned char* srcImg, int regionOff, unsigned char* ldsImg) {
    const unsigned char* s0 = srcImg + regionOff + t * 16;
    unsigned char* d0 = ldsImg + regionOff + w * 1024;   // wave-uniform dst
    gload16(s0, d0);
    gload16(s0 + 8192, d0 + 8192);
  };

  // tile body: single VM0+BAR at end (count-independent; race-class-free).
  auto tile = [&](int h, i32x8v (&xcur)[2][2], i32x8v (&xnext)[2][2]) {
    const unsigned char* Wcur = (h & 1) ? pW1 : pW0;
    unsigned char* Wnxt = &Wls[(h + 1) & 1][0];
    readB(bU, Wcur, 0, 0);
    readB(bV, Wcur, 0, 1);
    if (h + 1 < NKT2) {
      loadXg(xnext, h + 1);                      // 8 global b128 (plain)
      const unsigned char* wsrc = wbase + (size_t)(h + 1) * IMGB;
      stage(wsrc, 0,    Wnxt);                   // 4 gload16 total
      stage(wsrc, REGB, Wnxt);
    }
    quad(xcur[0], bU, 0);
    readB(bU, Wcur, 1, 0);
    quad(xcur[0], bV, 1);
    readB(bV, Wcur, 1, 1);
    quad(xcur[1], bU, 0);
    quad(xcur[1], bV, 1);
    VM0;                                         // X(h+1)+W(h+1) landed
    BAR();                                       // Wnxt visible; Wcur reads done
  };

  // prologue
  stage(wbase, 0,    &Wls[0][0]);
  stage(wbase, REGB, &Wls[0][0]);
  loadXg(xa, 0);
  VM0;
  BAR();

  for (int h = 0; h < NKT2; h += 2) {
    tile(h,     xa, xb);
    tile(h + 1, xb, xa);
  }

  // ---- epilogue: row sums of squares; undo 64x A-scale (x 2^-12) -----------
  // acc[mt][nf] reg r: row = tile_m*256 + (wr4*2+mt)*32 + (r&3) + 8*(r>>2) + 4*hi
  float v[2][16];
#pragma unroll
  for (int mt = 0; mt < 2; ++mt)
#pragma unroll
    for (int r = 0; r < 16; ++r) {
      float s = 0.f;
#pragma unroll
      for (int nf = 0; nf < 4; ++nf) {
        float c = acc[mt][nf][r];
        s += c * c;
      }
      s += __shfl_xor(s, 1, 64);
      s += __shfl_xor(s, 2, 64);
      s += __shfl_xor(s, 4, 64);
      s += __shfl_xor(s, 8, 64);
      s += __shfl_xor(s, 16, 64);
      v[mt][r] = s;
    }

  if ((lane & 31) == 0) {
#pragma unroll
    for (int mt = 0; mt < 2; ++mt)
#pragma unroll
      for (int r = 0; r < 16; ++r)
        rowsum[wc2][(wr4 * 2 + mt) * 32 + (r & 3) + 8 * (r >> 2) + 4 * hi] = v[mt][r];
  }
  __syncthreads();

  if (t < 256) {
    float p = (rowsum[0][t] + rowsum[1][t]) * (1.0f / 4096.0f);
    atomicAdd(&out[tile_m * 256 + t], p);
  }
}

// ---------------- fallback (direct fp32 path, used only if ws too small) ----
__device__ __forceinline__ bf16x8 pack8(const float4& a, const float4& b) {
  bf16x8 r;
  r[0] = (__bf16)a.x; r[1] = (__bf16)a.y; r[2] = (__bf16)a.z; r[3] = (__bf16)a.w;
  r[4] = (__bf16)b.x; r[5] = (__bf16)b.y; r[6] = (__bf16)b.z; r[7] = (__bf16)b.w;
  return r;
}

struct Stage {
  float4 x0a, x0b, x1a, x1b;
  float4 a0a, a0b, a1a, a1b;
};

__global__ __launch_bounds__(256) void gemm_rowsq(const float* __restrict__ X,
                                                  const float* __restrict__ A,
                                                  float* __restrict__ out) {
  __shared__ __align__(16) __bf16 Xs[128 * 32];
  __shared__ __align__(16) __bf16 As[128 * 32];
  __shared__ float rowsum[2][128];

  const int t    = threadIdx.x;
  const int lane = t & 63;
  const int wid  = t >> 6;
  const int wr   = wid >> 1;
  const int wc   = wid & 1;
  const int l15  = lane & 15;
  const int lg   = lane >> 4;

  unsigned bid = blockIdx.x;
  unsigned swz = (bid & 7) * 256u + (bid >> 3);
  const int tile_m = swz >> 5;
  const int tile_n = swz & 31;

  const int srow = t >> 2;
  const int sc   = t & 3;
  const int cw   = sc ^ ((t >> 3) & 3);
  const int woff = srow * 32 + cw * 8;

  const float* gx = X + (size_t)(tile_m * 128 + srow) * DK + sc * 8;
  const float* ga = A + (size_t)(tile_n * 128 + srow) * DK + sc * 8;

  const int chA  = lg ^ ((l15 >> 1) & 3);
  const int aoff = (wr * 64 + l15) * 32 + chA * 8;
  const int boff = (wc * 64 + l15) * 32 + chA * 8;

  f32x4 acc[4][4] = {};

  auto load_tile = [&](int kt) {
    Stage s;
    const float* px = gx + kt * 32;
    const float* pa = ga + kt * 32;
    s.x0a = *(const float4*)(px);
    s.x0b = *(const float4*)(px + 4);
    s.x1a = *(const float4*)(px + (size_t)64 * DK);
    s.x1b = *(const float4*)(px + (size_t)64 * DK + 4);
    s.a0a = *(const float4*)(pa);
    s.a0b = *(const float4*)(pa + 4);
    s.a1a = *(const float4*)(pa + (size_t)64 * DK);
    s.a1b = *(const float4*)(pa + (size_t)64 * DK + 4);
    return s;
  };

  auto store_stage = [&](const Stage& s) {
    *(bf16x8*)(Xs + woff)            = pack8(s.x0a, s.x0b);
    *(bf16x8*)(Xs + woff + 64 * 32)  = pack8(s.x1a, s.x1b);
    *(bf16x8*)(As + woff)            = pack8(s.a0a, s.a0b);
    *(bf16x8*)(As + woff + 64 * 32)  = pack8(s.a1a, s.a1b);
  };

  auto compute = [&]() {
    bf16x8 af[4], bfr[4];
#pragma unroll
    for (int m = 0; m < 4; ++m)
      af[m] = *(const bf16x8*)(Xs + aoff + m * 16 * 32);
#pragma unroll
    for (int n = 0; n < 4; ++n)
      bfr[n] = *(const bf16x8*)(As + boff + n * 16 * 32);
#pragma unroll
    for (int m = 0; m < 4; ++m)
#pragma unroll
      for (int n = 0; n < 4; ++n)
        acc[m][n] = __builtin_amdgcn_mfma_f32_16x16x32_bf16(af[m], bfr[n],
                                                            acc[m][n], 0, 0, 0);
  };

  Stage sa = load_tile(0), sb;

  for (int kt = 0; kt < 128; kt += 2) {
    __syncthreads();
    store_stage(sa);
    sb = load_tile(kt + 1);
    __syncthreads();
    compute();
    __syncthreads();
    store_stage(sb);
    if (kt + 2 < 128) sa = load_tile(kt + 2);
    __syncthreads();
    compute();
  }

  float v[4][4];
#pragma unroll
  for (int m = 0; m < 4; ++m)
#pragma unroll
    for (int j = 0; j < 4; ++j) {
      float s = 0.f;
#pragma unroll
      for (int n = 0; n < 4; ++n) {
        float c = acc[m][n][j];
        s += c * c;
      }
      s += __shfl_xor(s, 1, 64);
      s += __shfl_xor(s, 2, 64);
      s += __shfl_xor(s, 4, 64);
      s += __shfl_xor(s, 8, 64);
      v[m][j] = s;
    }

  if (l15 == 0) {
#pragma unroll
    for (int m = 0; m < 4; ++m)
#pragma unroll
      for (int j = 0; j < 4; ++j)
        rowsum[wc][wr * 64 + m * 16 + lg * 4 + j] = v[m][j];
  }
  __syncthreads();

  if (t < 128) {
    float p = rowsum[0][t] + rowsum[1][t];
    atomicAdd(&out[tile_m * 128 + t], p);
  }
}

extern "C" void kernel_launch(void* const* d_in, const int* in_sizes, int n_in,
                              void* d_out, int out_size, void* d_ws, size_t ws_size,
                              hipStream_t stream) {
  const float* x = (const float*)d_in[0];
  const float* A = (const float*)d_in[1];
  float* out = (float*)d_out;

  hipMemsetAsync(out, 0, (size_t)out_size * sizeof(float), stream);

  if (ws_size >= WS_NEED) {
    unsigned char* wsX = (unsigned char*)d_ws;
    unsigned char* wsW = wsX + X_BYTES;
    hipLaunchKernelGGL(convF8, dim3(2048), dim3(256), 0, stream, x, wsX, XT2, 1.0f);
    hipLaunchKernelGGL(convF8, dim3(2048), dim3(256), 0, stream, A, wsW, WT2, 64.0f);
    hipLaunchKernelGGL(gemm19, dim3(512), dim3(512), 0, stream, wsX, wsW, out);
  } else {
    hipLaunchKernelGGL(gemm_rowsq, dim3(2048), dim3(256), 0, stream, x, A, out);
  }
}

// Round 18
// 164.852 us; speedup vs baseline: 3.3674x; 3.3242x over previous
//
#include <hip/hip_runtime.h>
#include <hip/hip_fp8.h>

typedef __bf16 bf16x8 __attribute__((ext_vector_type(8)));
typedef float  f32x4  __attribute__((ext_vector_type(4)));
typedef float  f32x16 __attribute__((ext_vector_type(16)));
typedef int    i32x4v __attribute__((ext_vector_type(4)));
typedef int    i32x8v __attribute__((ext_vector_type(8)));
typedef unsigned char uchar16v __attribute__((ext_vector_type(16)));

#define NROWS 8192
#define DK    4096
#define MCOLS 4096

// ---- fp8 path geometry: BK=128 ---------------------------------------------
#define NKT2   32            // K-tiles of BK=128
#define IMGB   32768         // bytes per 256x128 fp8 tile image (32 KB)
#define REGB   16384         // region bytes (ki half)
#define XT2    32            // 8192/256
#define WT2    16            // 4096/256

#define X_BYTES ((size_t)XT2 * NKT2 * IMGB)   // 33.5 MB
#define W_BYTES ((size_t)WT2 * NKT2 * IMGB)   // 16.8 MB
#define WS_NEED (X_BYTES + W_BYTES)

#define BAR()  do { __builtin_amdgcn_s_barrier(); asm volatile("" ::: "memory"); } while (0)
#define VM0    asm volatile("s_waitcnt vmcnt(0)" ::: "memory")

__device__ __forceinline__ void gload16(const unsigned char* g, unsigned char* l) {
  __builtin_amdgcn_global_load_lds(
      (const __attribute__((address_space(1))) void*)g,
      (__attribute__((address_space(3))) void*)l, 16, 0, 0);
}

// fp32 row-major -> e4m3 fragment image:
// [tile][kt'][ki 0..1][slot 0..7][half 0..1][lane 0..63][16B]
__global__ __launch_bounds__(256) void convF8(const float* __restrict__ src,
                                              unsigned char* __restrict__ dst,
                                              int ntiles, float scale) {
  const int total = ntiles * 65536;
  for (int i = blockIdx.x * blockDim.x + threadIdx.x; i < total;
       i += gridDim.x * blockDim.x) {
    int lane = i & 63;
    int half = (i >> 6) & 1;
    int slot = (i >> 7) & 7;
    int ki   = (i >> 10) & 1;
    int kt   = (i >> 11) & 31;
    int tm   = i >> 16;
    int row = tm * 256 + slot * 32 + (lane & 31);
    int k   = kt * 128 + ki * 64 + (lane >> 5) * 32 + half * 16;
    const float4* p = (const float4*)(src + (size_t)row * DK + k);
    uchar16v o;
#pragma unroll
    for (int q = 0; q < 4; ++q) {
      float4 f = p[q];
      o[q * 4 + 0] = __hip_fp8_e4m3(f.x * scale).__x;
      o[q * 4 + 1] = __hip_fp8_e4m3(f.y * scale).__x;
      o[q * 4 + 2] = __hip_fp8_e4m3(f.z * scale).__x;
      o[q * 4 + 3] = __hip_fp8_e4m3(f.w * scale).__x;
    }
    *(uchar16v*)(dst + (size_t)i * 16) = o;
  }
}

// ---- X half-tile in registers (<=128 arch VGPR), W 2-buf LDS ---------------
__global__ __launch_bounds__(512, 2) void gemm20(const unsigned char* __restrict__ wsX,
                                                 const unsigned char* __restrict__ wsW,
                                                 float* __restrict__ out) {
  __shared__ __align__(16) unsigned char Wls[2][IMGB];   // 64 KB
  __shared__ float rowsum[2][256];

  const int t    = threadIdx.x;
  const int lane = t & 63;
  const int w    = t >> 6;           // 0..7
  const int wr4  = w >> 1;           // rows wr4*64..+63 (slots 2wr4, 2wr4+1)
  const int wc2  = w & 1;            // cols wc2*128..+127 (slots wc2*4..+3)
  const int hi   = lane >> 5;

  unsigned bid = blockIdx.x;
  unsigned xcd = bid & 7, seq = bid >> 3;
  const int tile_m = (int)((xcd >> 1) * 8 + (seq & 7));    // 0..31
  const int tile_n = (int)((xcd & 1) * 8 + (seq >> 3));    // 0..15

  const unsigned char* xbase = wsX + (size_t)tile_m * ((size_t)NKT2 * IMGB);
  const unsigned char* wbase = wsW + (size_t)tile_n * ((size_t)NKT2 * IMGB);

  const unsigned char* xw  = xbase + wr4 * 4096 + (size_t)lane * 16;
  const unsigned char* pW0 = &Wls[0][0] + wc2 * 8192 + lane * 16;
  const unsigned char* pW1 = &Wls[1][0] + wc2 * 8192 + lane * 16;

  f32x16 acc[2][4] = {};     // 128 acc regs
  i32x8v xA[2], xB[2];       // one ki-half each: 16+16 arch regs
  i32x8v bU[2], bV[2];       // 16+16 arch regs

  auto ld32 = [&](const unsigned char* p) {
    i32x4v lo = *(const i32x4v*)p;
    i32x4v hh = *(const i32x4v*)(p + 1024);
    i32x8v r;
    r[0] = lo[0]; r[1] = lo[1]; r[2] = lo[2]; r[3] = lo[3];
    r[4] = hh[0]; r[5] = hh[1]; r[6] = hh[2]; r[7] = hh[3];
    return r;
  };

  auto loadXhalf = [&](i32x8v (&x)[2], int h, int ki) {   // 4 global b128 (plain)
    const unsigned char* p = xw + (size_t)h * IMGB + ki * REGB;
#pragma unroll
    for (int mt = 0; mt < 2; ++mt)
      x[mt] = ld32(p + mt * 2048);
  };

  auto readB = [&](i32x8v (&b)[2], const unsigned char* p, int ki, int bh) { // 4 ds_read
#pragma unroll
    for (int nf2 = 0; nf2 < 2; ++nf2)
      b[nf2] = ld32(p + ki * REGB + (bh * 2 + nf2) * 2048);
  };

  auto quad = [&](const i32x8v (&a2)[2], const i32x8v (&b)[2], int bh) {  // 4 MFMA
    __builtin_amdgcn_s_setprio(1);
#pragma unroll
    for (int mt = 0; mt < 2; ++mt)
#pragma unroll
      for (int nf2 = 0; nf2 < 2; ++nf2)
        acc[mt][bh * 2 + nf2] = __builtin_amdgcn_mfma_scale_f32_32x32x64_f8f6f4(
            a2[mt], b[nf2], acc[mt][bh * 2 + nf2],
            0, 0,                    // cbsz/blgp = FP8 e4m3
            0, 0x7F7F7F7F,           // scale A = 1.0
            0, 0x7F7F7F7F);          // scale B = 1.0
    __builtin_amdgcn_s_setprio(0);
  };

  auto stage = [&](const unsigned char* srcImg, int regionOff, unsigned char* ldsImg) {
    const unsigned char* s0 = srcImg + regionOff + t * 16;
    unsigned char* d0 = ldsImg + regionOff + w * 1024;   // wave-uniform dst
    gload16(s0, d0);
    gload16(s0 + 8192, d0 + 8192);
  };

  // Invariant: entering tile h, xA = X(h, ki0); W(h) resident in buf[h&1].
  auto tile = [&](int h) {
    const unsigned char* Wcur = (h & 1) ? pW1 : pW0;
    unsigned char* Wnxt = &Wls[(h + 1) & 1][0];
    const bool more = (h + 1 < NKT2);

    // ph1: consume ki0; prefetch X(h,ki1) + stage W(h+1)
    readB(bU, Wcur, 0, 0);
    readB(bV, Wcur, 0, 1);
    loadXhalf(xB, h, 1);                         // compiler-tracked dep
    if (more) {
      const unsigned char* wsrc = wbase + (size_t)(h + 1) * IMGB;
      stage(wsrc, 0,    Wnxt);
      stage(wsrc, REGB, Wnxt);
    }
    quad(xA, bU, 0);
    quad(xA, bV, 1);

    // ph2: consume ki1; prefetch X(h+1,ki0)
    readB(bU, Wcur, 1, 0);
    readB(bV, Wcur, 1, 1);
    if (more) loadXhalf(xA, h + 1, 0);           // next-tile invariant
    quad(xB, bU, 0);
    quad(xB, bV, 1);

    VM0;                                         // own W-stage gloads landed
    BAR();                                       // all waves: Wnxt ready, Wcur reads done
  };

  // prologue
  stage(wbase, 0,    &Wls[0][0]);
  stage(wbase, REGB, &Wls[0][0]);
  loadXhalf(xA, 0, 0);
  VM0;
  BAR();

  for (int h = 0; h < NKT2; ++h) tile(h);

  // ---- epilogue: row sums of squares; undo 64x A-scale (x 2^-12) -----------
  // acc[mt][nf] reg r: row = tile_m*256 + (wr4*2+mt)*32 + (r&3) + 8*(r>>2) + 4*hi
  float v[2][16];
#pragma unroll
  for (int mt = 0; mt < 2; ++mt)
#pragma unroll
    for (int r = 0; r < 16; ++r) {
      float s = 0.f;
#pragma unroll
      for (int nf = 0; nf < 4; ++nf) {
        float c = acc[mt][nf][r];
        s += c * c;
      }
      s += __shfl_xor(s, 1, 64);
      s += __shfl_xor(s, 2, 64);
      s += __shfl_xor(s, 4, 64);
      s += __shfl_xor(s, 8, 64);
      s += __shfl_xor(s, 16, 64);
      v[mt][r] = s;
    }

  if ((lane & 31) == 0) {
#pragma unroll
    for (int mt = 0; mt < 2; ++mt)
#pragma unroll
      for (int r = 0; r < 16; ++r)
        rowsum[wc2][(wr4 * 2 + mt) * 32 + (r & 3) + 8 * (r >> 2) + 4 * hi] = v[mt][r];
  }
  __syncthreads();

  if (t < 256) {
    float p = (rowsum[0][t] + rowsum[1][t]) * (1.0f / 4096.0f);
    atomicAdd(&out[tile_m * 256 + t], p);
  }
}

// ---------------- fallback (direct fp32 path, used only if ws too small) ----
__device__ __forceinline__ bf16x8 pack8(const float4& a, const float4& b) {
  bf16x8 r;
  r[0] = (__bf16)a.x; r[1] = (__bf16)a.y; r[2] = (__bf16)a.z; r[3] = (__bf16)a.w;
  r[4] = (__bf16)b.x; r[5] = (__bf16)b.y; r[6] = (__bf16)b.z; r[7] = (__bf16)b.w;
  return r;
}

struct Stage {
  float4 x0a, x0b, x1a, x1b;
  float4 a0a, a0b, a1a, a1b;
};

__global__ __launch_bounds__(256) void gemm_rowsq(const float* __restrict__ X,
                                                  const float* __restrict__ A,
                                                  float* __restrict__ out) {
  __shared__ __align__(16) __bf16 Xs[128 * 32];
  __shared__ __align__(16) __bf16 As[128 * 32];
  __shared__ float rowsum[2][128];

  const int t    = threadIdx.x;
  const int lane = t & 63;
  const int wid  = t >> 6;
  const int wr   = wid >> 1;
  const int wc   = wid & 1;
  const int l15  = lane & 15;
  const int lg   = lane >> 4;

  unsigned bid = blockIdx.x;
  unsigned swz = (bid & 7) * 256u + (bid >> 3);
  const int tile_m = swz >> 5;
  const int tile_n = swz & 31;

  const int srow = t >> 2;
  const int sc   = t & 3;
  const int cw   = sc ^ ((t >> 3) & 3);
  const int woff = srow * 32 + cw * 8;

  const float* gx = X + (size_t)(tile_m * 128 + srow) * DK + sc * 8;
  const float* ga = A + (size_t)(tile_n * 128 + srow) * DK + sc * 8;

  const int chA  = lg ^ ((l15 >> 1) & 3);
  const int aoff = (wr * 64 + l15) * 32 + chA * 8;
  const int boff = (wc * 64 + l15) * 32 + chA * 8;

  f32x4 acc[4][4] = {};

  auto load_tile = [&](int kt) {
    Stage s;
    const float* px = gx + kt * 32;
    const float* pa = ga + kt * 32;
    s.x0a = *(const float4*)(px);
    s.x0b = *(const float4*)(px + 4);
    s.x1a = *(const float4*)(px + (size_t)64 * DK);
    s.x1b = *(const float4*)(px + (size_t)64 * DK + 4);
    s.a0a = *(const float4*)(pa);
    s.a0b = *(const float4*)(pa + 4);
    s.a1a = *(const float4*)(pa + (size_t)64 * DK);
    s.a1b = *(const float4*)(pa + (size_t)64 * DK + 4);
    return s;
  };

  auto store_stage = [&](const Stage& s) {
    *(bf16x8*)(Xs + woff)            = pack8(s.x0a, s.x0b);
    *(bf16x8*)(Xs + woff + 64 * 32)  = pack8(s.x1a, s.x1b);
    *(bf16x8*)(As + woff)            = pack8(s.a0a, s.a0b);
    *(bf16x8*)(As + woff + 64 * 32)  = pack8(s.a1a, s.a1b);
  };

  auto compute = [&]() {
    bf16x8 af[4], bfr[4];
#pragma unroll
    for (int m = 0; m < 4; ++m)
      af[m] = *(const bf16x8*)(Xs + aoff + m * 16 * 32);
#pragma unroll
    for (int n = 0; n < 4; ++n)
      bfr[n] = *(const bf16x8*)(As + boff + n * 16 * 32);
#pragma unroll
    for (int m = 0; m < 4; ++m)
#pragma unroll
      for (int n = 0; n < 4; ++n)
        acc[m][n] = __builtin_amdgcn_mfma_f32_16x16x32_bf16(af[m], bfr[n],
                                                            acc[m][n], 0, 0, 0);
  };

  Stage sa = load_tile(0), sb;

  for (int kt = 0; kt < 128; kt += 2) {
    __syncthreads();
    store_stage(sa);
    sb = load_tile(kt + 1);
    __syncthreads();
    compute();
    __syncthreads();
    store_stage(sb);
    if (kt + 2 < 128) sa = load_tile(kt + 2);
    __syncthreads();
    compute();
  }

  float v[4][4];
#pragma unroll
  for (int m = 0; m < 4; ++m)
#pragma unroll
    for (int j = 0; j < 4; ++j) {
      float s = 0.f;
#pragma unroll
      for (int n = 0; n < 4; ++n) {
        float c = acc[m][n][j];
        s += c * c;
      }
      s += __shfl_xor(s, 1, 64);
      s += __shfl_xor(s, 2, 64);
      s += __shfl_xor(s, 4, 64);
      s += __shfl_xor(s, 8, 64);
      v[m][j] = s;
    }

  if (l15 == 0) {
#pragma unroll
    for (int m = 0; m < 4; ++m)
#pragma unroll
      for (int j = 0; j < 4; ++j)
        rowsum[wc][wr * 64 + m * 16 + lg * 4 + j] = v[m][j];
  }
  __syncthreads();

  if (t < 128) {
    float p = rowsum[0][t] + rowsum[1][t];
    atomicAdd(&out[tile_m * 128 + t], p);
  }
}

extern "C" void kernel_launch(void* const* d_in, const int* in_sizes, int n_in,
                              void* d_out, int out_size, void* d_ws, size_t ws_size,
                              hipStream_t stream) {
  const float* x = (const float*)d_in[0];
  const float* A = (const float*)d_in[1];
  float* out = (float*)d_out;

  hipMemsetAsync(out, 0, (size_t)out_size * sizeof(float), stream);

  if (ws_size >= WS_NEED) {
    unsigned char* wsX = (unsigned char*)d_ws;
    unsigned char* wsW = wsX + X_BYTES;
    hipLaunchKernelGGL(convF8, dim3(2048), dim3(256), 0, stream, x, wsX, XT2, 1.0f);
    hipLaunchKernelGGL(convF8, dim3(2048), dim3(256), 0, stream, A, wsW, WT2, 64.0f);
    hipLaunchKernelGGL(gemm20, dim3(512), dim3(512), 0, stream, wsX, wsW, out);
  } else {
    hipLaunchKernelGGL(gemm_rowsq, dim3(2048), dim3(256), 0, stream, x, A, out);
  }
}

// Round 19
// 158.671 us; speedup vs baseline: 3.4986x; 1.0390x over previous
//
#include <hip/hip_runtime.h>
#include <hip/hip_fp8.h>

typedef __bf16 bf16x8 __attribute__((ext_vector_type(8)));
typedef float  f32x4  __attribute__((ext_vector_type(4)));
typedef float  f32x16 __attribute__((ext_vector_type(16)));
typedef int    i32x4v __attribute__((ext_vector_type(4)));
typedef int    i32x8v __attribute__((ext_vector_type(8)));
typedef unsigned char uchar16v __attribute__((ext_vector_type(16)));

#define NROWS 8192
#define DK    4096
#define MCOLS 4096

// ---- fp8 path geometry: BK=128 ---------------------------------------------
#define NKT2   32            // K-tiles of BK=128
#define IMGB   32768         // bytes per 256x128 fp8 tile image (32 KB)
#define REGB   16384         // region bytes (ki half)
#define XT2    32            // 8192/256
#define WT2    16            // 4096/256

#define X_BYTES ((size_t)XT2 * NKT2 * IMGB)   // 33.5 MB
#define W_BYTES ((size_t)WT2 * NKT2 * IMGB)   // 16.8 MB
#define WS_NEED (X_BYTES + W_BYTES)

#define BAR()  do { __builtin_amdgcn_s_barrier(); asm volatile("" ::: "memory"); } while (0)
#define LGKM0  asm volatile("s_waitcnt lgkmcnt(0)" ::: "memory")
#define VM(n)  asm volatile("s_waitcnt vmcnt(" #n ")" ::: "memory")

__device__ __forceinline__ void gload16(const unsigned char* g, unsigned char* l) {
  __builtin_amdgcn_global_load_lds(
      (const __attribute__((address_space(1))) void*)g,
      (__attribute__((address_space(3))) void*)l, 16, 0, 0);
}

// fp32 row-major -> e4m3 fragment image:
// [tile][kt'][ki 0..1][slot 0..7][half 0..1][lane 0..63][16B]
__global__ __launch_bounds__(256) void convF8(const float* __restrict__ src,
                                              unsigned char* __restrict__ dst,
                                              int ntiles, float scale) {
  const int total = ntiles * 65536;
  for (int i = blockIdx.x * blockDim.x + threadIdx.x; i < total;
       i += gridDim.x * blockDim.x) {
    int lane = i & 63;
    int half = (i >> 6) & 1;
    int slot = (i >> 7) & 7;
    int ki   = (i >> 10) & 1;
    int kt   = (i >> 11) & 31;
    int tm   = i >> 16;
    int row = tm * 256 + slot * 32 + (lane & 31);
    int k   = kt * 128 + ki * 64 + (lane >> 5) * 32 + half * 16;
    const float4* p = (const float4*)(src + (size_t)row * DK + k);
    uchar16v o;
#pragma unroll
    for (int q = 0; q < 4; ++q) {
      float4 f = p[q];
      o[q * 4 + 0] = __hip_fp8_e4m3(f.x * scale).__x;
      o[q * 4 + 1] = __hip_fp8_e4m3(f.y * scale).__x;
      o[q * 4 + 2] = __hip_fp8_e4m3(f.z * scale).__x;
      o[q * 4 + 3] = __hip_fp8_e4m3(f.w * scale).__x;
    }
    *(uchar16v*)(dst + (size_t)i * 16) = o;
  }
}

// ---- session-best (R15): 8-phase ledger, 1 barrier/phase, phase-ahead reads
__global__ __launch_bounds__(512, 2) void gemm18(const unsigned char* __restrict__ wsX,
                                                 const unsigned char* __restrict__ wsW,
                                                 float* __restrict__ out) {
  __shared__ __align__(16) unsigned char Xls[2][IMGB];   // 64 KB
  __shared__ __align__(16) unsigned char Wls[2][IMGB];   // 64 KB
  __shared__ float rowsum[2][256];

  const int t    = threadIdx.x;
  const int lane = t & 63;
  const int w    = t >> 6;           // 0..7
  const int wr4  = w >> 1;           // rows wr4*64..+63 (slots 2wr4, 2wr4+1)
  const int wc2  = w & 1;            // cols wc2*128..+127 (slots wc2*4..+3)
  const int hi   = lane >> 5;

  unsigned bid = blockIdx.x;
  unsigned xcd = bid & 7, seq = bid >> 3;
  const int tile_m = (int)((xcd >> 1) * 8 + (seq & 7));    // 0..31
  const int tile_n = (int)((xcd & 1) * 8 + (seq >> 3));    // 0..15

  const unsigned char* xbase = wsX + (size_t)tile_m * ((size_t)NKT2 * IMGB);
  const unsigned char* wbase = wsW + (size_t)tile_n * ((size_t)NKT2 * IMGB);

  const unsigned char* pX0 = &Xls[0][0] + wr4 * 4096 + lane * 16;
  const unsigned char* pX1 = &Xls[1][0] + wr4 * 4096 + lane * 16;
  const unsigned char* pW0 = &Wls[0][0] + wc2 * 8192 + lane * 16;
  const unsigned char* pW1 = &Wls[1][0] + wc2 * 8192 + lane * 16;

  f32x16 acc[2][4] = {};     // [mt][nf] : 128 VGPR
  i32x8v aP[2], aN[2], bP[2], bQ[2], bR[2], bS[2];

  auto ld32 = [&](const unsigned char* p) {
    i32x4v lo = *(const i32x4v*)p;
    i32x4v hh = *(const i32x4v*)(p + 1024);
    i32x8v r;
    r[0] = lo[0]; r[1] = lo[1]; r[2] = lo[2]; r[3] = lo[3];
    r[4] = hh[0]; r[5] = hh[1]; r[6] = hh[2]; r[7] = hh[3];
    return r;
  };

  auto readA = [&](i32x8v (&a)[2], const unsigned char* p, int ki) {
#pragma unroll
    for (int mt = 0; mt < 2; ++mt)
      a[mt] = ld32(p + ki * REGB + mt * 2048);
  };

  auto readB = [&](i32x8v (&b)[2], const unsigned char* p, int ki, int bh) {
#pragma unroll
    for (int nf2 = 0; nf2 < 2; ++nf2)
      b[nf2] = ld32(p + ki * REGB + (bh * 2 + nf2) * 2048);
  };

  auto quad = [&](const i32x8v (&a)[2], const i32x8v (&b)[2], int bh) {
    __builtin_amdgcn_s_setprio(1);
#pragma unroll
    for (int mt = 0; mt < 2; ++mt)
#pragma unroll
      for (int nf2 = 0; nf2 < 2; ++nf2)
        acc[mt][bh * 2 + nf2] = __builtin_amdgcn_mfma_scale_f32_32x32x64_f8f6f4(
            a[mt], b[nf2], acc[mt][bh * 2 + nf2],
            0, 0,                    // cbsz/blgp = FP8 e4m3
            0, 0x7F7F7F7F,           // scale A = 1.0
            0, 0x7F7F7F7F);          // scale B = 1.0
    __builtin_amdgcn_s_setprio(0);
  };

  auto stage = [&](const unsigned char* srcImg, int regionOff, unsigned char* ldsImg) {
    const unsigned char* s0 = srcImg + regionOff + t * 16;
    unsigned char* d0 = ldsImg + regionOff + w * 1024;   // wave-uniform dst
    gload16(s0, d0);
    gload16(s0 + 8192, d0 + 8192);
  };

  // prologue (verified FIFO): VM(8) forces X0(0),W0(0)
  stage(xbase,         0,    &Xls[0][0]);   // X0(0)
  stage(wbase,         0,    &Wls[0][0]);   // W0(0)
  stage(xbase,         REGB, &Xls[0][0]);   // X1(0)
  stage(wbase,         REGB, &Wls[0][0]);   // W1(0)
  stage(xbase + IMGB,  0,    &Xls[1][0]);   // X0(1)
  stage(wbase + IMGB,  0,    &Wls[1][0]);   // W0(1)
  VM(8);
  BAR();

  for (int it = 0; it < 15; ++it) {
    const int h0 = 2 * it;
    const unsigned char* xi1 = xbase + (size_t)(h0 + 1) * IMGB;
    const unsigned char* wi1 = wbase + (size_t)(h0 + 1) * IMGB;
    const unsigned char* xi2 = xbase + (size_t)(h0 + 2) * IMGB;
    const unsigned char* wi2 = wbase + (size_t)(h0 + 2) * IMGB;
    const unsigned char* xi3 = xbase + (size_t)(h0 + 3) * IMGB;
    const unsigned char* wi3 = wbase + (size_t)(h0 + 3) * IMGB;

    // ---- half-iter A: tile h0 in buf0 (one barrier per phase) ----
    // p1
    readA(aP, pX0, 0); readB(bP, pW0, 0, 0); readB(bQ, pW0, 0, 1);
    stage(xi1, REGB, &Xls[1][0]);                 // X1(h0+1)
    quad(aP, bP, 0); VM(6); BAR();                // forces X1,W1(h0)
    // p2
    readA(aN, pX0, 1); readB(bR, pW0, 1, 0);
    stage(wi1, REGB, &Wls[1][0]);                 // W1(h0+1)
    quad(aP, bQ, 1); BAR();
    // p3
    readB(bS, pW0, 1, 1);
    stage(xi2, 0, &Xls[0][0]);                    // X0(h0+2)
    quad(aN, bR, 0); BAR();
    // p4
    stage(wi2, 0, &Wls[0][0]);                    // W0(h0+2)
    quad(aN, bS, 1); VM(8); BAR();                // forces X0,W0(h0+1)

    // ---- half-iter B: tile h0+1 in buf1 ----
    readA(aP, pX1, 0); readB(bP, pW1, 0, 0); readB(bQ, pW1, 0, 1);
    stage(xi2, REGB, &Xls[0][0]);                 // X1(h0+2)
    quad(aP, bP, 0); VM(6); BAR();                // forces X1,W1(h0+1)
    readA(aN, pX1, 1); readB(bR, pW1, 1, 0);
    stage(wi2, REGB, &Wls[0][0]);                 // W1(h0+2)
    quad(aP, bQ, 1); BAR();
    readB(bS, pW1, 1, 1);
    stage(xi3, 0, &Xls[1][0]);                    // X0(h0+3)
    quad(aN, bR, 0); BAR();
    stage(wi3, 0, &Wls[1][0]);                    // W0(h0+3)
    quad(aN, bS, 1); VM(8); BAR();                // forces X0,W0(h0+2)
  }

  // ---- peeled tail: tiles 30 (buf0), 31 (buf1) — verified form -------------
  {
    const unsigned char* xi1 = xbase + (size_t)31 * IMGB;
    const unsigned char* wi1 = wbase + (size_t)31 * IMGB;

    readA(aP, pX0, 0); readB(bP, pW0, 0, 0);
    stage(xi1, REGB, &Xls[1][0]);                 // X1(31)
    BAR(); LGKM0; quad(aP, bP, 0); VM(6); BAR();  // forces X1,W1(30)
    readB(bQ, pW0, 0, 1);
    stage(wi1, REGB, &Wls[1][0]);                 // W1(31)
    BAR(); LGKM0; quad(aP, bQ, 1); BAR();
    readA(aN, pX0, 1); readB(bR, pW0, 1, 0);
    BAR(); LGKM0; quad(aN, bR, 0); BAR();
    readB(bS, pW0, 1, 1);
    BAR(); LGKM0; quad(aN, bS, 1); VM(4); BAR();  // forces X0,W0(31)
    readA(aP, pX1, 0); readB(bP, pW1, 0, 0);
    BAR(); LGKM0; quad(aP, bP, 0); VM(0); BAR();  // forces X1,W1(31)
    readB(bQ, pW1, 0, 1);
    BAR(); LGKM0; quad(aP, bQ, 1); BAR();
    readA(aN, pX1, 1); readB(bR, pW1, 1, 0);
    BAR(); LGKM0; quad(aN, bR, 0); BAR();
    readB(bS, pW1, 1, 1);
    LGKM0; quad(aN, bS, 1);
  }

  // ---- epilogue: row sums of squares; undo 64x A-scale (x 2^-12) -----------
  float v[2][16];
#pragma unroll
  for (int mt = 0; mt < 2; ++mt)
#pragma unroll
    for (int r = 0; r < 16; ++r) {
      float s = 0.f;
#pragma unroll
      for (int nf = 0; nf < 4; ++nf) {
        float c = acc[mt][nf][r];
        s += c * c;
      }
      s += __shfl_xor(s, 1, 64);
      s += __shfl_xor(s, 2, 64);
      s += __shfl_xor(s, 4, 64);
      s += __shfl_xor(s, 8, 64);
      s += __shfl_xor(s, 16, 64);
      v[mt][r] = s;
    }

  if ((lane & 31) == 0) {
#pragma unroll
    for (int mt = 0; mt < 2; ++mt)
#pragma unroll
      for (int r = 0; r < 16; ++r)
        rowsum[wc2][(wr4 * 2 + mt) * 32 + (r & 3) + 8 * (r >> 2) + 4 * hi] = v[mt][r];
  }
  __syncthreads();

  if (t < 256) {
    float p = (rowsum[0][t] + rowsum[1][t]) * (1.0f / 4096.0f);
    atomicAdd(&out[tile_m * 256 + t], p);
  }
}

// ---------------- fallback (direct fp32 path, used only if ws too small) ----
__device__ __forceinline__ bf16x8 pack8(const float4& a, const float4& b) {
  bf16x8 r;
  r[0] = (__bf16)a.x; r[1] = (__bf16)a.y; r[2] = (__bf16)a.z; r[3] = (__bf16)a.w;
  r[4] = (__bf16)b.x; r[5] = (__bf16)b.y; r[6] = (__bf16)b.z; r[7] = (__bf16)b.w;
  return r;
}

struct Stage {
  float4 x0a, x0b, x1a, x1b;
  float4 a0a, a0b, a1a, a1b;
};

__global__ __launch_bounds__(256) void gemm_rowsq(const float* __restrict__ X,
                                                  const float* __restrict__ A,
                                                  float* __restrict__ out) {
  __shared__ __align__(16) __bf16 Xs[128 * 32];
  __shared__ __align__(16) __bf16 As[128 * 32];
  __shared__ float rowsum[2][128];

  const int t    = threadIdx.x;
  const int lane = t & 63;
  const int wid  = t >> 6;
  const int wr   = wid >> 1;
  const int wc   = wid & 1;
  const int l15  = lane & 15;
  const int lg   = lane >> 4;

  unsigned bid = blockIdx.x;
  unsigned swz = (bid & 7) * 256u + (bid >> 3);
  const int tile_m = swz >> 5;
  const int tile_n = swz & 31;

  const int srow = t >> 2;
  const int sc   = t & 3;
  const int cw   = sc ^ ((t >> 3) & 3);
  const int woff = srow * 32 + cw * 8;

  const float* gx = X + (size_t)(tile_m * 128 + srow) * DK + sc * 8;
  const float* ga = A + (size_t)(tile_n * 128 + srow) * DK + sc * 8;

  const int chA  = lg ^ ((l15 >> 1) & 3);
  const int aoff = (wr * 64 + l15) * 32 + chA * 8;
  const int boff = (wc * 64 + l15) * 32 + chA * 8;

  f32x4 acc[4][4] = {};

  auto load_tile = [&](int kt) {
    Stage s;
    const float* px = gx + kt * 32;
    const float* pa = ga + kt * 32;
    s.x0a = *(const float4*)(px);
    s.x0b = *(const float4*)(px + 4);
    s.x1a = *(const float4*)(px + (size_t)64 * DK);
    s.x1b = *(const float4*)(px + (size_t)64 * DK + 4);
    s.a0a = *(const float4*)(pa);
    s.a0b = *(const float4*)(pa + 4);
    s.a1a = *(const float4*)(pa + (size_t)64 * DK);
    s.a1b = *(const float4*)(pa + (size_t)64 * DK + 4);
    return s;
  };

  auto store_stage = [&](const Stage& s) {
    *(bf16x8*)(Xs + woff)            = pack8(s.x0a, s.x0b);
    *(bf16x8*)(Xs + woff + 64 * 32)  = pack8(s.x1a, s.x1b);
    *(bf16x8*)(As + woff)            = pack8(s.a0a, s.a0b);
    *(bf16x8*)(As + woff + 64 * 32)  = pack8(s.a1a, s.a1b);
  };

  auto compute = [&]() {
    bf16x8 af[4], bfr[4];
#pragma unroll
    for (int m = 0; m < 4; ++m)
      af[m] = *(const bf16x8*)(Xs + aoff + m * 16 * 32);
#pragma unroll
    for (int n = 0; n < 4; ++n)
      bfr[n] = *(const bf16x8*)(As + boff + n * 16 * 32);
#pragma unroll
    for (int m = 0; m < 4; ++m)
#pragma unroll
      for (int n = 0; n < 4; ++n)
        acc[m][n] = __builtin_amdgcn_mfma_f32_16x16x32_bf16(af[m], bfr[n],
                                                            acc[m][n], 0, 0, 0);
  };

  Stage sa = load_tile(0), sb;

  for (int kt = 0; kt < 128; kt += 2) {
    __syncthreads();
    store_stage(sa);
    sb = load_tile(kt + 1);
    __syncthreads();
    compute();
    __syncthreads();
    store_stage(sb);
    if (kt + 2 < 128) sa = load_tile(kt + 2);
    __syncthreads();
    compute();
  }

  float v[4][4];
#pragma unroll
  for (int m = 0; m < 4; ++m)
#pragma unroll
    for (int j = 0; j < 4; ++j) {
      float s = 0.f;
#pragma unroll
      for (int n = 0; n < 4; ++n) {
        float c = acc[m][n][j];
        s += c * c;
      }
      s += __shfl_xor(s, 1, 64);
      s += __shfl_xor(s, 2, 64);
      s += __shfl_xor(s, 4, 64);
      s += __shfl_xor(s, 8, 64);
      v[m][j] = s;
    }

  if (l15 == 0) {
#pragma unroll
    for (int m = 0; m < 4; ++m)
#pragma unroll
      for (int j = 0; j < 4; ++j)
        rowsum[wc][wr * 64 + m * 16 + lg * 4 + j] = v[m][j];
  }
  __syncthreads();

  if (t < 128) {
    float p = rowsum[0][t] + rowsum[1][t];
    atomicAdd(&out[tile_m * 128 + t], p);
  }
}

extern "C" void kernel_launch(void* const* d_in, const int* in_sizes, int n_in,
                              void* d_out, int out_size, void* d_ws, size_t ws_size,
                              hipStream_t stream) {
  const float* x = (const float*)d_in[0];
  const float* A = (const float*)d_in[1];
  float* out = (float*)d_out;

  hipMemsetAsync(out, 0, (size_t)out_size * sizeof(float), stream);

  if (ws_size >= WS_NEED) {
    unsigned char* wsX = (unsigned char*)d_ws;
    unsigned char* wsW = wsX + X_BYTES;
    hipLaunchKernelGGL(convF8, dim3(2048), dim3(256), 0, stream, x, wsX, XT2, 1.0f);
    hipLaunchKernelGGL(convF8, dim3(2048), dim3(256), 0, stream, A, wsW, WT2, 64.0f);
    hipLaunchKernelGGL(gemm18, dim3(512), dim3(512), 0, stream, wsX, wsW, out);
  } else {
    hipLaunchKernelGGL(gemm_rowsq, dim3(2048), dim3(256), 0, stream, x, A, out);
  }
}